// Round 11
// baseline (199.863 us; speedup 1.0000x reference)
//
#include <hip/hip_runtime.h>
#include <hip/hip_bf16.h>
#include <math.h>

#define BLK 64
#define EPB 16            // elements per block (one wave)
#define NF 32
#define THIST 15

typedef __attribute__((ext_vector_type(8))) short s16x8;  // 8 bf16 = 4 VGPRs
typedef __attribute__((ext_vector_type(4))) float f32x4;
typedef __attribute__((ext_vector_type(2))) float f32x2;  // -> v_pk_* f32 ops

union frag_u { s16x8 v; unsigned u[4]; };

__device__ __forceinline__ float frcp(float x) {
    return __builtin_amdgcn_rcpf(x);
}
__device__ __forceinline__ unsigned packbf2(float x0, float x1) {
    __hip_bfloat162 b = __float22bfloat162_rn(float2{x0, x1});
    union { __hip_bfloat162 b; unsigned u; } c; c.b = b; return c.u;
}
// tanh for the uniform Riccati prologue only
__device__ __forceinline__ float tanhfe(float x) {
    float e = __expf(2.0f * x);
    return fmaf(-2.0f, frcp(e + 1.0f), 1.0f);
}

// P = F P F^T for the constant-accel F (dt=0.2), in place (uniform Riccati only)
__device__ __forceinline__ void fpft(float (&P)[6][6]) {
    const float dt = 0.2f, hd = 0.02f;
    #pragma unroll
    for (int j = 0; j < 6; ++j) {
        float a0 = P[0][j] + dt * P[1][j] + hd * P[2][j];
        float a1 = P[1][j] + dt * P[2][j];
        float a3 = P[3][j] + dt * P[4][j] + hd * P[5][j];
        float a4 = P[4][j] + dt * P[5][j];
        P[0][j] = a0; P[1][j] = a1; P[3][j] = a3; P[4][j] = a4;
    }
    #pragma unroll
    for (int i = 0; i < 6; ++i) {
        float a0 = P[i][0] + dt * P[i][1] + hd * P[i][2];
        float a1 = P[i][1] + dt * P[i][2];
        float a3 = P[i][3] + dt * P[i][4] + hd * P[i][5];
        float a4 = P[i][4] + dt * P[i][5];
        P[i][0] = a0; P[i][1] = a1; P[i][3] = a3; P[i][4] = a4;
    }
}

// ------------------------------- main kernel ---------------------------------
// R11 = R10 with the NaN fixed: inline-asm v_exp_f32 (exp2raw) hid a TRANS op
// from the compiler's hazard recognizer -> consumer read the result register
// before the trans pipe wrote it -> garbage/NaN. Fix: exp2f() (OCML ->
// compiler-emitted v_exp_f32 with proper wait states). Same single trans op.
//  (a) ZERO-PERMLANE layout: permute MFMA A-ROW assignments so each lane's D
//      output IS its B-operand k-slice (D row m=4s+r -> feature 8s+4blk+r).
//      Deletes all 8 permlanes/step + 2 serial cross-lane deps. BIT-IDENTICAL.
//  (b) exp2-folding on SIGMOID gates: i/f/o weights+bias pre-scaled by
//      -log2(e) -> e^-g = 2^gfs = one v_exp_f32, no pre-multiply.
__global__ __launch_bounds__(BLK, 2)
void kalman_lstm(const float* __restrict__ hist,
                 const float* __restrict__ psx, const float* __restrict__ psy,
                 const float* __restrict__ vsx, const float* __restrict__ vsy,
                 const float* __restrict__ asx, const float* __restrict__ asy,
                 const float* __restrict__ jerk, const float* __restrict__ coefG,
                 const float* __restrict__ GRv,
                 const float* __restrict__ cfW, const float* __restrict__ cfb,
                 const float* __restrict__ Wih, const float* __restrict__ Whh,
                 const float* __restrict__ bih, const float* __restrict__ bhh,
                 const float* __restrict__ coW, const float* __restrict__ cob,
                 float* __restrict__ out, int B, int len_pred)
{
    __shared__ float kf[216];  // [t*12..+11]=K pairs (paired layout); [180..215]=P_hist

    const int lane = threadIdx.x;
    const int e = lane & 15;              // element slot (MFMA n-index / D col)
    const int s = lane >> 4;              // quad (k-slice / D row group)
    const int b = blockIdx.x * EPB + e;

    const float dt = 0.2f, hd = 0.02f;
    const float g0 = dt * dt * dt / 6.0f, g1 = 0.02f, g2 = dt;
    const float NL2E = -1.4426950408889634f;   // -log2(e)
    float ga0 = g0 * tanhf(coefG[0]);
    float ga1 = g1 * tanhf(coefG[1]);
    float ga2 = g2 * tanhf(coefG[2]);
    float gb3 = g0 * tanhf(coefG[3]);
    float gb4 = g1 * tanhf(coefG[4]);
    float gb5 = g2 * tanhf(coefG[5]);

    // ---- batch-uniform Kalman-gain recursion (verbatim math; lane0 writes) ----
    // K stored PAIRED for packed consumption:
    //  t*12: {K0[0],K0[3], K0[1],K0[4], K0[2],K0[5], K1[0],K1[3], K1[1],K1[4], K1[2],K1[5]}
    {
        float j0 = jerk[0], j1 = jerk[1];
        float gr0 = GRv[0], gr1 = GRv[1];
        float R00 = gr0 * gr0, R01 = gr0 * gr1, R11 = gr1 * gr1;
        float qa[3] = {ga0 * j0, ga1 * j0, ga2 * j0};
        float qb[3] = {gb3 * j1, gb4 * j1, gb5 * j1};

        float Pk[6][6];
        #pragma unroll
        for (int i = 0; i < 6; ++i)
            #pragma unroll
            for (int j = 0; j < 6; ++j) Pk[i][j] = 0.0f;
        { float v;
          v = psx[0]; Pk[0][0] = v * v;
          v = vsx[0]; Pk[1][1] = v * v;
          v = asx[0]; Pk[2][2] = v * v;
          v = psy[0]; Pk[3][3] = v * v;
          v = vsy[0]; Pk[4][4] = v * v;
          v = asy[0]; Pk[5][5] = v * v; }

        #pragma unroll 1
        for (int t = 0; t < THIST; ++t) {
            fpft(Pk);
            #pragma unroll
            for (int i = 0; i < 3; ++i)
                #pragma unroll
                for (int j = 0; j < 3; ++j) {
                    Pk[i][j]         += qa[i] * qa[j];
                    Pk[3 + i][3 + j] += qb[i] * qb[j];
                }
            float S00 = Pk[0][0] + R00;
            float S01 = Pk[0][3] + R01;
            float S11 = Pk[3][3] + R11;
            float idet = 1.0f / (S00 * S11 - S01 * S01);
            float i00 =  S11 * idet, i01 = -S01 * idet, i11 = S00 * idet;
            float K0[6], K1[6];
            #pragma unroll
            for (int i = 0; i < 6; ++i) {
                K0[i] = Pk[i][0] * i00 + Pk[i][3] * i01;
                K1[i] = Pk[i][0] * i01 + Pk[i][3] * i11;
            }
            if (lane == 0) {
                #pragma unroll
                for (int i = 0; i < 3; ++i) {
                    kf[t * 12 + 2 * i]     = K0[i];
                    kf[t * 12 + 2 * i + 1] = K0[3 + i];
                    kf[t * 12 + 6 + 2 * i]     = K1[i];
                    kf[t * 12 + 6 + 2 * i + 1] = K1[3 + i];
                }
            }
            #pragma unroll
            for (int i = 0; i < 6; ++i) {
                Pk[i][1] -= K0[1] * Pk[i][0] + K1[1] * Pk[i][3];
                Pk[i][2] -= K0[2] * Pk[i][0] + K1[2] * Pk[i][3];
                Pk[i][4] -= K0[4] * Pk[i][0] + K1[4] * Pk[i][3];
                Pk[i][5] -= K0[5] * Pk[i][0] + K1[5] * Pk[i][3];
                float t0 = Pk[i][0] - (K0[0] * Pk[i][0] + K1[0] * Pk[i][3]);
                float t3 = Pk[i][3] - (K0[3] * Pk[i][0] + K1[3] * Pk[i][3]);
                Pk[i][0] = t0; Pk[i][3] = t3;
            }
        }
        if (lane == 0) {
            #pragma unroll
            for (int i = 0; i < 6; ++i)
                #pragma unroll
                for (int j = 0; j < 6; ++j) kf[180 + i * 6 + j] = Pk[i][j];
        }
    }

    // ---- LSTM weights, ROW-PERMUTED + sigmoid-scaled ----
    // Tile nt: gate G=nt>>1 (0=i,1=f,2=g,3=o), blk=nt&1.
    // Lane-e A-row = W row G*32 + 8*(e>>2) + 4*blk + (e&3)  (bijective per G).
    // D row m=4s+r then holds gate value for feature 8s+4*blk+r == lane's
    // k-slice -> h/feat fragments need NO cross-lane exchange.
    // Sigmoid gates (G!=2) pre-scaled by -log2(e) for raw-2^x consumption.
    s16x8 wih_h[8], whh_h[8];
    #pragma unroll
    for (int nt = 0; nt < 8; ++nt) {
        int G = nt >> 1, blk = nt & 1;
        float sc = (G == 2) ? 1.0f : NL2E;
        int base = (G * 32 + 8 * (e >> 2) + 4 * blk + (e & 3)) * NF + s * 8;
        frag_u ih_h, hh_h;
        #pragma unroll
        for (int q = 0; q < 4; ++q) {
            ih_h.u[q] = packbf2(sc * Wih[base + 2 * q], sc * Wih[base + 2 * q + 1]);
            hh_h.u[q] = packbf2(sc * Whh[base + 2 * q], sc * Whh[base + 2 * q + 1]);
        }
        wih_h[nt] = ih_h.v;
        whh_h[nt] = hh_h.v;
    }

    // bias fragments (register C-in), same row permutation + scale:
    // lane (e,s) C[r] -> feature row G*32 + 8s + 4*blk + r (r contiguous)
    f32x4 biasF[8];
    #pragma unroll
    for (int nt = 0; nt < 8; ++nt) {
        int G = nt >> 1, blk = nt & 1;
        float sc = (G == 2) ? 1.0f : NL2E;
        int base = G * 32 + 8 * s + 4 * blk;
        f32x4 bi = *(const f32x4*)&bih[base];
        f32x4 bh = *(const f32x4*)&bhh[base];
        biasF[nt] = (bi + bh) * sc;
    }

    // feat-MFMA A-frags, row-permuted: tile0 lane-e row -> feature
    // 8*(e>>2)+(e&3), tile1 -> +4. s=0 lanes carry cfW + cfb at k=6.
    s16x8 cfwA0, cfwA1;
    {
        frag_u fa0, fa1; fa0.v = (s16x8)0; fa1.v = (s16x8)0;
        if (s == 0) {
            int f0 = 8 * (e >> 2) + (e & 3);
            int f1 = f0 + 4;
            const float* w0 = cfW + f0 * 6;
            const float* w1 = cfW + f1 * 6;
            fa0.u[0] = packbf2(w0[0], w0[1]);
            fa0.u[1] = packbf2(w0[2], w0[3]);
            fa0.u[2] = packbf2(w0[4], w0[5]);
            fa0.u[3] = packbf2(cfb[f0], 0.0f);
            fa1.u[0] = packbf2(w1[0], w1[1]);
            fa1.u[1] = packbf2(w1[2], w1[3]);
            fa1.u[2] = packbf2(w1[4], w1[5]);
            fa1.u[3] = packbf2(cfb[f1], 0.0f);
        }
        cfwA0 = fa0.v; cfwA1 = fa1.v;
    }
    // cmd-MFMA A-frag: coW rows replicated 4x -> D[m=4s+r] = cmd_r in every lane
    s16x8 cmdA;
    {
        frag_u ca;
        const float* cp = coW + (e & 3) * NF + 8 * s;
        #pragma unroll
        for (int q = 0; q < 4; ++q)
            ca.u[q] = packbf2(cp[2 * q], cp[2 * q + 1]);
        cmdA = ca.v;
    }
    f32x4 cobC = {cob[0], cob[1], cob[2], cob[3]};

    // ---- Kalman state X, PACKED: Xa={X0,X3}, Xb={X1,X4}, Xc={X2,X5} ----
    const float2* hist2 = (const float2*)hist;
    float2 z0 = hist2[b];
    float2 z1 = hist2[B + b];
    f32x2 Xa = {z0.x, (z1.y - z0.y) / dt};
    f32x2 Xb = {(z1.x - z0.x) / dt, 0.0f};
    f32x2 Xc = {0.0f, 0.0f};

    float creg[8];
    #pragma unroll
    for (int j = 0; j < 8; ++j) creg[j] = 0.0f;
    s16x8 ah_h = (s16x8)0;

    __syncthreads();   // one-time: kf visible

    auto lstm_step = [&]() {
        // ---- feat via MFMA: featpre = cfW@X + cfb ----
        frag_u xb;
        xb.u[0] = packbf2(Xa.x, Xb.x);            // X0,X1
        xb.u[1] = packbf2(Xc.x, Xa.y);            // X2,X3
        xb.u[2] = packbf2(Xb.y, Xc.y);            // X4,X5
        xb.u[3] = 0x00003f80u;                    // k6 = bf16(1.0)
        const f32x4 zc4 = {0.0f, 0.0f, 0.0f, 0.0f};
        f32x4 fp0 = __builtin_amdgcn_mfma_f32_16x16x32_bf16(cfwA0, xb.v, zc4, 0, 0, 0);
        f32x4 fp1 = __builtin_amdgcn_mfma_f32_16x16x32_bf16(cfwA1, xb.v, zc4, 0, 0, 0);
        // fp0[r] = featpre[8s+r], fp1[r] = featpre[8s+4+r]: tanh + DIRECT pack
        auto tanhq = [](float x) {
            float eg = __expf(2.0f * x);
            return fmaf(-2.0f, frcp(eg + 1.0f), 1.0f);
        };
        frag_u af;
        af.u[0] = packbf2(tanhq(fp0[0]), tanhq(fp0[1]));
        af.u[1] = packbf2(tanhq(fp0[2]), tanhq(fp0[3]));
        af.u[2] = packbf2(tanhq(fp1[0]), tanhq(fp1[1]));
        af.u[3] = packbf2(tanhq(fp1[2]), tanhq(fp1[3]));

        // ---- gates = Wih@feat + Whh@h + bias (register C-in) ----
        f32x4 acc[8];
        #pragma unroll
        for (int nt = 0; nt < 8; ++nt) {
            acc[nt] = __builtin_amdgcn_mfma_f32_16x16x32_bf16(wih_h[nt], af.v, biasF[nt], 0, 0, 0);
            acc[nt] = __builtin_amdgcn_mfma_f32_16x16x32_bf16(whh_h[nt], ah_h, acc[nt], 0, 0, 0);
        }

        // combine; sigmoid gates arrive PRE-SCALED by -log2e -> exp2f (single
        // v_exp_f32, compiler-managed trans hazard — R10's inline asm hid it).
        //   cn = c*rcp(1+2^gf') + (eg-1)*rcp((1+2^gi')(eg+1)),  eg = e^2gg
        //   hv = (ec-1)*rcp((1+2^go')(ec+1)),                    ec = e^2cn
        unsigned whx[2][2];
        #pragma unroll
        for (int blk = 0; blk < 2; ++blk) {
            float hv[4];
            #pragma unroll
            for (int r = 0; r < 4; ++r) {
                float gis = acc[0 + blk][r];
                float gfs = acc[2 + blk][r];
                float gg  = acc[4 + blk][r];
                float gos = acc[6 + blk][r];
                float ef = exp2f(gfs);
                float ei = exp2f(gis);
                float eg = __expf(2.0f * gg);
                float r1 = frcp(1.0f + ef);
                float r2 = frcp((1.0f + ei) * (eg + 1.0f));
                float cn = fmaf(eg - 1.0f, r2, creg[4 * blk + r] * r1);
                creg[4 * blk + r] = cn;
                float eo = exp2f(gos);
                float ec = __expf(2.0f * cn);
                hv[r] = (ec - 1.0f) * frcp((1.0f + eo) * (ec + 1.0f));
            }
            #pragma unroll
            for (int rp = 0; rp < 2; ++rp)
                whx[blk][rp] = packbf2(hv[2 * rp], hv[2 * rp + 1]);
        }

        // hv[blk][r] = h[8s+4blk+r] -> ah fragment packs DIRECTLY (no exchange)
        frag_u ahh;
        ahh.u[0] = whx[0][0];
        ahh.u[1] = whx[0][1];
        ahh.u[2] = whx[1][0];
        ahh.u[3] = whx[1][1];
        ah_h = ahh.v;
    };

    // ------------- history phase: packed X update, uniform K from LDS -------------
    float2 zc = z1;
    #pragma unroll 1
    for (int t = 0; t < THIST; ++t) {
        int tn = (t + 2 < 16) ? (t + 2) : 15;
        float2 zn = hist2[(size_t)tn * B + b];
        f32x4 k0 = *(const f32x4*)&kf[t * 12];       // {K00,K03,K01,K04}
        f32x4 k1 = *(const f32x4*)&kf[t * 12 + 4];   // {K02,K05,K10,K13}
        f32x4 k2 = *(const f32x4*)&kf[t * 12 + 8];   // {K11,K14,K12,K15}

        lstm_step();

        Xa = Xa + dt * Xb + hd * Xc;
        Xb = Xb + dt * Xc;
        float y0 = zc.x - Xa.x, y1 = zc.y - Xa.y;
        f32x2 kA0 = {k0[0], k0[1]}, kB0 = {k0[2], k0[3]}, kC0 = {k1[0], k1[1]};
        f32x2 kA1 = {k1[2], k1[3]}, kB1 = {k2[0], k2[1]}, kC1 = {k2[2], k2[3]};
        Xa = Xa + kA0 * y0 + kA1 * y1;
        Xb = Xb + kB0 * y0 + kB1 * y1;
        Xc = Xc + kC0 * y0 + kC1 * y1;
        zc = zn;
    }

    // P init; x/y blocks PACKED {x, y}
    f32x2 pxy00 = {kf[180], kf[201]}, pxy01 = {kf[181], kf[202]},
          pxy02 = {kf[182], kf[203]}, pxy11 = {kf[187], kf[208]},
          pxy12 = {kf[188], kf[209]}, pxy22 = {kf[194], kf[214]};
    float c00 = kf[183], c01 = kf[184], c02 = kf[185],
          c10 = kf[189], c11 = kf[190], c12 = kf[191],
          c20 = kf[195], c21 = kf[196], c22 = kf[197];
    const f32x2 gaP0 = {ga0, gb3}, gaP1 = {ga1, gb4}, gaP2 = {ga2, gb5};

    // ---------------- prediction phase ----------------
    #pragma unroll 1
    for (int tp = 0; tp < len_pred; ++tp) {
        lstm_step();

        // cmd = coW@h + cob via one MFMA; every lane gets cmd0..3 in D regs
        f32x4 cm = __builtin_amdgcn_mfma_f32_16x16x32_bf16(cmdA, ah_h, cobC, 0, 0, 0);
        f32x2 cmdP  = {cm[0], cm[1]};
        f32x2 cmd23 = {cm[2], cm[3]};

        Xa = Xa + dt * Xb + hd * Xc + g0 * cmdP;
        Xb = Xb + dt * Xc + g1 * cmdP;
        Xc = Xc + g2 * cmdP;

        // P = F P F^T + Gs Gs^T; x/y blocks packed, cross scalar
        f32x2 gsA = gaP0 * cmd23;   // {gs0, gs3}
        f32x2 gsB = gaP1 * cmd23;   // {gs1, gs4}
        f32x2 gsC = gaP2 * cmd23;   // {gs2, gs5}
        {
            f32x2 r00 = pxy00 + dt * pxy01 + hd * pxy02;
            f32x2 r01 = pxy01 + dt * pxy11 + hd * pxy12;
            f32x2 r02 = pxy02 + dt * pxy12 + hd * pxy22;
            f32x2 r11 = pxy11 + dt * pxy12;
            f32x2 r12 = pxy12 + dt * pxy22;
            pxy00 = r00 + dt * r01 + hd * r02;
            pxy01 = r01 + dt * r02;
            pxy02 = r02;
            pxy11 = r11 + dt * r12;
            pxy12 = r12;
            pxy00 += gsA * gsA; pxy01 += gsA * gsB; pxy02 += gsA * gsC;
            pxy11 += gsB * gsB; pxy12 += gsB * gsC; pxy22 += gsC * gsC;
        }
        {   // cross block c = A c A^T + gs_x gs_y^T (scalar)
            float gs0 = gsA.x, gs1 = gsB.x, gs2 = gsC.x;
            float gs3 = gsA.y, gs4 = gsB.y, gs5 = gsC.y;
            float q00 = c00 + dt * c10 + hd * c20;
            float q01 = c01 + dt * c11 + hd * c21;
            float q02 = c02 + dt * c12 + hd * c22;
            float q10 = c10 + dt * c20;
            float q11 = c11 + dt * c21;
            float q12 = c12 + dt * c22;
            c00 = q00 + dt * q01 + hd * q02;
            c01 = q01 + dt * q02;
            c02 = q02;
            c10 = q10 + dt * q11 + hd * q12;
            c11 = q11 + dt * q12;
            c12 = q12;
            float n20 = c20 + dt * c21 + hd * c22;
            float n21 = c21 + dt * c22;
            c20 = n20; c21 = n21;
            c00 += gs0 * gs3; c01 += gs0 * gs4; c02 += gs0 * gs5;
            c10 += gs1 * gs3; c11 += gs1 * gs4; c12 += gs1 * gs5;
            c20 += gs2 * gs3; c21 += gs2 * gs4; c22 += gs2 * gs5;
        }

        float sx = sqrtf(pxy00.x), sy = sqrtf(pxy00.y);
        float rho = c00 / (sx * sy);
        if (s == 0) {
            size_t o = ((size_t)tp * B + b) * 5u;
            out[o + 0] = Xa.x;
            out[o + 1] = Xa.y;
            out[o + 2] = sx;
            out[o + 3] = sy;
            out[o + 4] = rho;
        }
    }
}

extern "C" void kernel_launch(void* const* d_in, const int* in_sizes, int n_in,
                              void* d_out, int out_size, void* d_ws, size_t ws_size,
                              hipStream_t stream) {
    const int T = 16;
    const int B = in_sizes[0] / (2 * T);      // 32768
    const int len_pred = out_size / (5 * B);  // 25
    (void)d_ws; (void)ws_size; (void)n_in;

    const int grid = (B + EPB - 1) / EPB;     // one wave per 16 elements
    kalman_lstm<<<grid, BLK, 0, stream>>>(
        (const float*)d_in[0],  (const float*)d_in[1],  (const float*)d_in[2],
        (const float*)d_in[3],  (const float*)d_in[4],  (const float*)d_in[5],
        (const float*)d_in[6],  (const float*)d_in[7],  (const float*)d_in[8],
        (const float*)d_in[9],  (const float*)d_in[10], (const float*)d_in[11],
        (const float*)d_in[12], (const float*)d_in[13], (const float*)d_in[14],
        (const float*)d_in[15], (const float*)d_in[16], (const float*)d_in[17],
        (float*)d_out, B, len_pred);
}

// Round 12
// 177.092 us; speedup vs baseline: 1.1286x; 1.1286x over previous
//
#include <hip/hip_runtime.h>
#include <hip/hip_bf16.h>
#include <math.h>

#define BLK 64
#define EPB 16            // elements per block (one wave)
#define NF 32
#define THIST 15

typedef __attribute__((ext_vector_type(8))) short s16x8;  // 8 bf16 = 4 VGPRs
typedef __attribute__((ext_vector_type(4))) float f32x4;
typedef __attribute__((ext_vector_type(2))) float f32x2;  // -> v_pk_* f32 ops

union frag_u { s16x8 v; unsigned u[4]; };

__device__ __forceinline__ float frcp(float x) {
    return __builtin_amdgcn_rcpf(x);
}
// raw v_exp_f32 via COMPILER BUILTIN (hazards handled; no OCML fixup).
// R11 lesson: exp2f() = precise OCML (+~5 instr fixup each); R10 lesson:
// inline-asm trans op hides the hazard -> NaN. Builtin is the safe fast path.
__device__ __forceinline__ float exp2b(float x) {
    return __builtin_amdgcn_exp2f(x);
}
__device__ __forceinline__ unsigned packbf2(float x0, float x1) {
    __hip_bfloat162 b = __float22bfloat162_rn(float2{x0, x1});
    union { __hip_bfloat162 b; unsigned u; } c; c.b = b; return c.u;
}
// tanh for the uniform Riccati prologue only
__device__ __forceinline__ float tanhfe(float x) {
    float e = __expf(2.0f * x);
    return fmaf(-2.0f, frcp(e + 1.0f), 1.0f);
}

// P = F P F^T for the constant-accel F (dt=0.2), in place (uniform Riccati only)
__device__ __forceinline__ void fpft(float (&P)[6][6]) {
    const float dt = 0.2f, hd = 0.02f;
    #pragma unroll
    for (int j = 0; j < 6; ++j) {
        float a0 = P[0][j] + dt * P[1][j] + hd * P[2][j];
        float a1 = P[1][j] + dt * P[2][j];
        float a3 = P[3][j] + dt * P[4][j] + hd * P[5][j];
        float a4 = P[4][j] + dt * P[5][j];
        P[0][j] = a0; P[1][j] = a1; P[3][j] = a3; P[4][j] = a4;
    }
    #pragma unroll
    for (int i = 0; i < 6; ++i) {
        float a0 = P[i][0] + dt * P[i][1] + hd * P[i][2];
        float a1 = P[i][1] + dt * P[i][2];
        float a3 = P[i][3] + dt * P[i][4] + hd * P[i][5];
        float a4 = P[i][4] + dt * P[i][5];
        P[i][0] = a0; P[i][1] = a1; P[i][3] = a3; P[i][4] = a4;
    }
}

// ------------------------------- main kernel ---------------------------------
// R12 = R11 with the exp regression fixed + full exp2 constant-folding:
//  - all hot-loop exps are __builtin_amdgcn_exp2f (single v_exp_f32).
//  - sigmoid gates (i/f/o): weights+bias pre-scaled by -log2(e).
//  - g-gate AND cfW/cfb: pre-scaled by 2*log2(e) -> tanh exps need no mul.
//  - ec = exp2(2log2e * cn): one mul (was two via __expf(2cn)).
//  - zero-permlane layout (R10a) retained: D rows == B k-slices by A-row
//    permutation; no cross-lane ops in the recurrence at all.
__global__ __launch_bounds__(BLK, 2)
void kalman_lstm(const float* __restrict__ hist,
                 const float* __restrict__ psx, const float* __restrict__ psy,
                 const float* __restrict__ vsx, const float* __restrict__ vsy,
                 const float* __restrict__ asx, const float* __restrict__ asy,
                 const float* __restrict__ jerk, const float* __restrict__ coefG,
                 const float* __restrict__ GRv,
                 const float* __restrict__ cfW, const float* __restrict__ cfb,
                 const float* __restrict__ Wih, const float* __restrict__ Whh,
                 const float* __restrict__ bih, const float* __restrict__ bhh,
                 const float* __restrict__ coW, const float* __restrict__ cob,
                 float* __restrict__ out, int B, int len_pred)
{
    __shared__ float kf[216];  // [t*12..+11]=K pairs (paired layout); [180..215]=P_hist

    const int lane = threadIdx.x;
    const int e = lane & 15;              // element slot (MFMA n-index / D col)
    const int s = lane >> 4;              // quad (k-slice / D row group)
    const int b = blockIdx.x * EPB + e;

    const float dt = 0.2f, hd = 0.02f;
    const float g0 = dt * dt * dt / 6.0f, g1 = 0.02f, g2 = dt;
    const float NL2E  = -1.4426950408889634f;   // -log2(e)
    const float T2L2E =  2.8853900817779268f;   // 2*log2(e)
    float ga0 = g0 * tanhf(coefG[0]);
    float ga1 = g1 * tanhf(coefG[1]);
    float ga2 = g2 * tanhf(coefG[2]);
    float gb3 = g0 * tanhf(coefG[3]);
    float gb4 = g1 * tanhf(coefG[4]);
    float gb5 = g2 * tanhf(coefG[5]);

    // ---- batch-uniform Kalman-gain recursion (verbatim math; lane0 writes) ----
    // K stored PAIRED for packed consumption:
    //  t*12: {K0[0],K0[3], K0[1],K0[4], K0[2],K0[5], K1[0],K1[3], K1[1],K1[4], K1[2],K1[5]}
    {
        float j0 = jerk[0], j1 = jerk[1];
        float gr0 = GRv[0], gr1 = GRv[1];
        float R00 = gr0 * gr0, R01 = gr0 * gr1, R11 = gr1 * gr1;
        float qa[3] = {ga0 * j0, ga1 * j0, ga2 * j0};
        float qb[3] = {gb3 * j1, gb4 * j1, gb5 * j1};

        float Pk[6][6];
        #pragma unroll
        for (int i = 0; i < 6; ++i)
            #pragma unroll
            for (int j = 0; j < 6; ++j) Pk[i][j] = 0.0f;
        { float v;
          v = psx[0]; Pk[0][0] = v * v;
          v = vsx[0]; Pk[1][1] = v * v;
          v = asx[0]; Pk[2][2] = v * v;
          v = psy[0]; Pk[3][3] = v * v;
          v = vsy[0]; Pk[4][4] = v * v;
          v = asy[0]; Pk[5][5] = v * v; }

        #pragma unroll 1
        for (int t = 0; t < THIST; ++t) {
            fpft(Pk);
            #pragma unroll
            for (int i = 0; i < 3; ++i)
                #pragma unroll
                for (int j = 0; j < 3; ++j) {
                    Pk[i][j]         += qa[i] * qa[j];
                    Pk[3 + i][3 + j] += qb[i] * qb[j];
                }
            float S00 = Pk[0][0] + R00;
            float S01 = Pk[0][3] + R01;
            float S11 = Pk[3][3] + R11;
            float idet = 1.0f / (S00 * S11 - S01 * S01);
            float i00 =  S11 * idet, i01 = -S01 * idet, i11 = S00 * idet;
            float K0[6], K1[6];
            #pragma unroll
            for (int i = 0; i < 6; ++i) {
                K0[i] = Pk[i][0] * i00 + Pk[i][3] * i01;
                K1[i] = Pk[i][0] * i01 + Pk[i][3] * i11;
            }
            if (lane == 0) {
                #pragma unroll
                for (int i = 0; i < 3; ++i) {
                    kf[t * 12 + 2 * i]     = K0[i];
                    kf[t * 12 + 2 * i + 1] = K0[3 + i];
                    kf[t * 12 + 6 + 2 * i]     = K1[i];
                    kf[t * 12 + 6 + 2 * i + 1] = K1[3 + i];
                }
            }
            #pragma unroll
            for (int i = 0; i < 6; ++i) {
                Pk[i][1] -= K0[1] * Pk[i][0] + K1[1] * Pk[i][3];
                Pk[i][2] -= K0[2] * Pk[i][0] + K1[2] * Pk[i][3];
                Pk[i][4] -= K0[4] * Pk[i][0] + K1[4] * Pk[i][3];
                Pk[i][5] -= K0[5] * Pk[i][0] + K1[5] * Pk[i][3];
                float t0 = Pk[i][0] - (K0[0] * Pk[i][0] + K1[0] * Pk[i][3]);
                float t3 = Pk[i][3] - (K0[3] * Pk[i][0] + K1[3] * Pk[i][3]);
                Pk[i][0] = t0; Pk[i][3] = t3;
            }
        }
        if (lane == 0) {
            #pragma unroll
            for (int i = 0; i < 6; ++i)
                #pragma unroll
                for (int j = 0; j < 6; ++j) kf[180 + i * 6 + j] = Pk[i][j];
        }
    }

    // ---- LSTM weights, ROW-PERMUTED + exp2-folded scales ----
    // Tile nt: gate G=nt>>1 (0=i,1=f,2=g,3=o), blk=nt&1.
    // Lane-e A-row = W row G*32 + 8*(e>>2) + 4*blk + (e&3)  (bijective per G).
    // D row m=4s+r holds gate value for feature 8s+4*blk+r == lane's k-slice.
    // Scales: sigmoid gates x(-log2e) -> 2^g = e^-g; g-gate x(2log2e) -> 2^g = e^2g.
    s16x8 wih_h[8], whh_h[8];
    #pragma unroll
    for (int nt = 0; nt < 8; ++nt) {
        int G = nt >> 1, blk = nt & 1;
        float sc = (G == 2) ? T2L2E : NL2E;
        int base = (G * 32 + 8 * (e >> 2) + 4 * blk + (e & 3)) * NF + s * 8;
        frag_u ih_h, hh_h;
        #pragma unroll
        for (int q = 0; q < 4; ++q) {
            ih_h.u[q] = packbf2(sc * Wih[base + 2 * q], sc * Wih[base + 2 * q + 1]);
            hh_h.u[q] = packbf2(sc * Whh[base + 2 * q], sc * Whh[base + 2 * q + 1]);
        }
        wih_h[nt] = ih_h.v;
        whh_h[nt] = hh_h.v;
    }

    // bias fragments (register C-in), same row permutation + scales
    f32x4 biasF[8];
    #pragma unroll
    for (int nt = 0; nt < 8; ++nt) {
        int G = nt >> 1, blk = nt & 1;
        float sc = (G == 2) ? T2L2E : NL2E;
        int base = G * 32 + 8 * s + 4 * blk;
        f32x4 bi = *(const f32x4*)&bih[base];
        f32x4 bh = *(const f32x4*)&bhh[base];
        biasF[nt] = (bi + bh) * sc;
    }

    // feat-MFMA A-frags, row-permuted AND x(2log2e): tile0 lane-e row ->
    // feature 8*(e>>2)+(e&3), tile1 -> +4. s=0 lanes carry cfW + cfb at k=6.
    // featpre arrives pre-scaled so tanh's exp is a raw 2^x.
    s16x8 cfwA0, cfwA1;
    {
        frag_u fa0, fa1; fa0.v = (s16x8)0; fa1.v = (s16x8)0;
        if (s == 0) {
            int f0 = 8 * (e >> 2) + (e & 3);
            int f1 = f0 + 4;
            const float* w0 = cfW + f0 * 6;
            const float* w1 = cfW + f1 * 6;
            fa0.u[0] = packbf2(T2L2E * w0[0], T2L2E * w0[1]);
            fa0.u[1] = packbf2(T2L2E * w0[2], T2L2E * w0[3]);
            fa0.u[2] = packbf2(T2L2E * w0[4], T2L2E * w0[5]);
            fa0.u[3] = packbf2(T2L2E * cfb[f0], 0.0f);
            fa1.u[0] = packbf2(T2L2E * w1[0], T2L2E * w1[1]);
            fa1.u[1] = packbf2(T2L2E * w1[2], T2L2E * w1[3]);
            fa1.u[2] = packbf2(T2L2E * w1[4], T2L2E * w1[5]);
            fa1.u[3] = packbf2(T2L2E * cfb[f1], 0.0f);
        }
        cfwA0 = fa0.v; cfwA1 = fa1.v;
    }
    // cmd-MFMA A-frag: coW rows replicated 4x -> D[m=4s+r] = cmd_r in every lane
    s16x8 cmdA;
    {
        frag_u ca;
        const float* cp = coW + (e & 3) * NF + 8 * s;
        #pragma unroll
        for (int q = 0; q < 4; ++q)
            ca.u[q] = packbf2(cp[2 * q], cp[2 * q + 1]);
        cmdA = ca.v;
    }
    f32x4 cobC = {cob[0], cob[1], cob[2], cob[3]};

    // ---- Kalman state X, PACKED: Xa={X0,X3}, Xb={X1,X4}, Xc={X2,X5} ----
    const float2* hist2 = (const float2*)hist;
    float2 z0 = hist2[b];
    float2 z1 = hist2[B + b];
    f32x2 Xa = {z0.x, (z1.y - z0.y) / dt};
    f32x2 Xb = {(z1.x - z0.x) / dt, 0.0f};
    f32x2 Xc = {0.0f, 0.0f};

    float creg[8];
    #pragma unroll
    for (int j = 0; j < 8; ++j) creg[j] = 0.0f;
    s16x8 ah_h = (s16x8)0;

    __syncthreads();   // one-time: kf visible

    auto lstm_step = [&]() {
        // ---- feat via MFMA: featpre' = 2log2e*(cfW@X + cfb) ----
        frag_u xb;
        xb.u[0] = packbf2(Xa.x, Xb.x);            // X0,X1
        xb.u[1] = packbf2(Xc.x, Xa.y);            // X2,X3
        xb.u[2] = packbf2(Xb.y, Xc.y);            // X4,X5
        xb.u[3] = 0x00003f80u;                    // k6 = bf16(1.0)
        const f32x4 zc4 = {0.0f, 0.0f, 0.0f, 0.0f};
        f32x4 fp0 = __builtin_amdgcn_mfma_f32_16x16x32_bf16(cfwA0, xb.v, zc4, 0, 0, 0);
        f32x4 fp1 = __builtin_amdgcn_mfma_f32_16x16x32_bf16(cfwA1, xb.v, zc4, 0, 0, 0);
        // tanh(p) = 1 - 2/(2^{p'}+1), p' = 2log2e*p — exp is a raw v_exp_f32
        auto tanhq = [](float xp) {
            float eg = exp2b(xp);
            return fmaf(-2.0f, frcp(eg + 1.0f), 1.0f);
        };
        frag_u af;
        af.u[0] = packbf2(tanhq(fp0[0]), tanhq(fp0[1]));
        af.u[1] = packbf2(tanhq(fp0[2]), tanhq(fp0[3]));
        af.u[2] = packbf2(tanhq(fp1[0]), tanhq(fp1[1]));
        af.u[3] = packbf2(tanhq(fp1[2]), tanhq(fp1[3]));

        // ---- gates = Wih@feat + Whh@h + bias (register C-in) ----
        f32x4 acc[8];
        #pragma unroll
        for (int nt = 0; nt < 8; ++nt) {
            acc[nt] = __builtin_amdgcn_mfma_f32_16x16x32_bf16(wih_h[nt], af.v, biasF[nt], 0, 0, 0);
            acc[nt] = __builtin_amdgcn_mfma_f32_16x16x32_bf16(whh_h[nt], ah_h, acc[nt], 0, 0, 0);
        }

        // combine; every exp is a raw 2^x (scales pre-folded):
        //   ef=2^gf'(=e^-gf)  ei=2^gi'  eg=2^gg'(=e^2gg)  eo=2^go'  ec=2^(2log2e*cn)
        //   cn = c*rcp(1+ef) + (eg-1)*rcp((1+ei)(eg+1))
        //   hv = (ec-1)*rcp((1+eo)(ec+1))
        unsigned whx[2][2];
        #pragma unroll
        for (int blk = 0; blk < 2; ++blk) {
            float hv[4];
            #pragma unroll
            for (int r = 0; r < 4; ++r) {
                float gis = acc[0 + blk][r];
                float gfs = acc[2 + blk][r];
                float ggs = acc[4 + blk][r];
                float gos = acc[6 + blk][r];
                float ef = exp2b(gfs);
                float ei = exp2b(gis);
                float eg = exp2b(ggs);
                float r1 = frcp(1.0f + ef);
                float r2 = frcp((1.0f + ei) * (eg + 1.0f));
                float cn = fmaf(eg - 1.0f, r2, creg[4 * blk + r] * r1);
                creg[4 * blk + r] = cn;
                float eo = exp2b(gos);
                float ec = exp2b(T2L2E * cn);
                hv[r] = (ec - 1.0f) * frcp((1.0f + eo) * (ec + 1.0f));
            }
            #pragma unroll
            for (int rp = 0; rp < 2; ++rp)
                whx[blk][rp] = packbf2(hv[2 * rp], hv[2 * rp + 1]);
        }

        // hv[blk][r] = h[8s+4blk+r] -> ah fragment packs DIRECTLY (no exchange)
        frag_u ahh;
        ahh.u[0] = whx[0][0];
        ahh.u[1] = whx[0][1];
        ahh.u[2] = whx[1][0];
        ahh.u[3] = whx[1][1];
        ah_h = ahh.v;
    };

    // ------------- history phase: packed X update, uniform K from LDS -------------
    float2 zc = z1;
    #pragma unroll 1
    for (int t = 0; t < THIST; ++t) {
        int tn = (t + 2 < 16) ? (t + 2) : 15;
        float2 zn = hist2[(size_t)tn * B + b];
        f32x4 k0 = *(const f32x4*)&kf[t * 12];       // {K00,K03,K01,K04}
        f32x4 k1 = *(const f32x4*)&kf[t * 12 + 4];   // {K02,K05,K10,K13}
        f32x4 k2 = *(const f32x4*)&kf[t * 12 + 8];   // {K11,K14,K12,K15}

        lstm_step();

        Xa = Xa + dt * Xb + hd * Xc;
        Xb = Xb + dt * Xc;
        float y0 = zc.x - Xa.x, y1 = zc.y - Xa.y;
        f32x2 kA0 = {k0[0], k0[1]}, kB0 = {k0[2], k0[3]}, kC0 = {k1[0], k1[1]};
        f32x2 kA1 = {k1[2], k1[3]}, kB1 = {k2[0], k2[1]}, kC1 = {k2[2], k2[3]};
        Xa = Xa + kA0 * y0 + kA1 * y1;
        Xb = Xb + kB0 * y0 + kB1 * y1;
        Xc = Xc + kC0 * y0 + kC1 * y1;
        zc = zn;
    }

    // P init; x/y blocks PACKED {x, y}
    f32x2 pxy00 = {kf[180], kf[201]}, pxy01 = {kf[181], kf[202]},
          pxy02 = {kf[182], kf[203]}, pxy11 = {kf[187], kf[208]},
          pxy12 = {kf[188], kf[209]}, pxy22 = {kf[194], kf[214]};
    float c00 = kf[183], c01 = kf[184], c02 = kf[185],
          c10 = kf[189], c11 = kf[190], c12 = kf[191],
          c20 = kf[195], c21 = kf[196], c22 = kf[197];
    const f32x2 gaP0 = {ga0, gb3}, gaP1 = {ga1, gb4}, gaP2 = {ga2, gb5};

    // ---------------- prediction phase ----------------
    #pragma unroll 1
    for (int tp = 0; tp < len_pred; ++tp) {
        lstm_step();

        // cmd = coW@h + cob via one MFMA; every lane gets cmd0..3 in D regs
        f32x4 cm = __builtin_amdgcn_mfma_f32_16x16x32_bf16(cmdA, ah_h, cobC, 0, 0, 0);
        f32x2 cmdP  = {cm[0], cm[1]};
        f32x2 cmd23 = {cm[2], cm[3]};

        Xa = Xa + dt * Xb + hd * Xc + g0 * cmdP;
        Xb = Xb + dt * Xc + g1 * cmdP;
        Xc = Xc + g2 * cmdP;

        // P = F P F^T + Gs Gs^T; x/y blocks packed, cross scalar
        f32x2 gsA = gaP0 * cmd23;   // {gs0, gs3}
        f32x2 gsB = gaP1 * cmd23;   // {gs1, gs4}
        f32x2 gsC = gaP2 * cmd23;   // {gs2, gs5}
        {
            f32x2 r00 = pxy00 + dt * pxy01 + hd * pxy02;
            f32x2 r01 = pxy01 + dt * pxy11 + hd * pxy12;
            f32x2 r02 = pxy02 + dt * pxy12 + hd * pxy22;
            f32x2 r11 = pxy11 + dt * pxy12;
            f32x2 r12 = pxy12 + dt * pxy22;
            pxy00 = r00 + dt * r01 + hd * r02;
            pxy01 = r01 + dt * r02;
            pxy02 = r02;
            pxy11 = r11 + dt * r12;
            pxy12 = r12;
            pxy00 += gsA * gsA; pxy01 += gsA * gsB; pxy02 += gsA * gsC;
            pxy11 += gsB * gsB; pxy12 += gsB * gsC; pxy22 += gsC * gsC;
        }
        {   // cross block c = A c A^T + gs_x gs_y^T (scalar)
            float gs0 = gsA.x, gs1 = gsB.x, gs2 = gsC.x;
            float gs3 = gsA.y, gs4 = gsB.y, gs5 = gsC.y;
            float q00 = c00 + dt * c10 + hd * c20;
            float q01 = c01 + dt * c11 + hd * c21;
            float q02 = c02 + dt * c12 + hd * c22;
            float q10 = c10 + dt * c20;
            float q11 = c11 + dt * c21;
            float q12 = c12 + dt * c22;
            c00 = q00 + dt * q01 + hd * q02;
            c01 = q01 + dt * q02;
            c02 = q02;
            c10 = q10 + dt * q11 + hd * q12;
            c11 = q11 + dt * q12;
            c12 = q12;
            float n20 = c20 + dt * c21 + hd * c22;
            float n21 = c21 + dt * c22;
            c20 = n20; c21 = n21;
            c00 += gs0 * gs3; c01 += gs0 * gs4; c02 += gs0 * gs5;
            c10 += gs1 * gs3; c11 += gs1 * gs4; c12 += gs1 * gs5;
            c20 += gs2 * gs3; c21 += gs2 * gs4; c22 += gs2 * gs5;
        }

        float sx = sqrtf(pxy00.x), sy = sqrtf(pxy00.y);
        float rho = c00 / (sx * sy);
        if (s == 0) {
            size_t o = ((size_t)tp * B + b) * 5u;
            out[o + 0] = Xa.x;
            out[o + 1] = Xa.y;
            out[o + 2] = sx;
            out[o + 3] = sy;
            out[o + 4] = rho;
        }
    }
}

extern "C" void kernel_launch(void* const* d_in, const int* in_sizes, int n_in,
                              void* d_out, int out_size, void* d_ws, size_t ws_size,
                              hipStream_t stream) {
    const int T = 16;
    const int B = in_sizes[0] / (2 * T);      // 32768
    const int len_pred = out_size / (5 * B);  // 25
    (void)d_ws; (void)ws_size; (void)n_in;

    const int grid = (B + EPB - 1) / EPB;     // one wave per 16 elements
    kalman_lstm<<<grid, BLK, 0, stream>>>(
        (const float*)d_in[0],  (const float*)d_in[1],  (const float*)d_in[2],
        (const float*)d_in[3],  (const float*)d_in[4],  (const float*)d_in[5],
        (const float*)d_in[6],  (const float*)d_in[7],  (const float*)d_in[8],
        (const float*)d_in[9],  (const float*)d_in[10], (const float*)d_in[11],
        (const float*)d_in[12], (const float*)d_in[13], (const float*)d_in[14],
        (const float*)d_in[15], (const float*)d_in[16], (const float*)d_in[17],
        (float*)d_out, B, len_pred);
}

// Round 13
// 173.270 us; speedup vs baseline: 1.1535x; 1.0221x over previous
//
#include <hip/hip_runtime.h>
#include <hip/hip_bf16.h>
#include <math.h>

#define BLK 64
#define EPB 16            // elements per block (one wave)
#define NF 32
#define THIST 15

typedef __attribute__((ext_vector_type(8))) short s16x8;  // 8 bf16 = 4 VGPRs
typedef __attribute__((ext_vector_type(4))) float f32x4;
typedef __attribute__((ext_vector_type(2))) float f32x2;  // -> v_pk_* f32 ops

union frag_u { s16x8 v; unsigned u[4]; };

__device__ __forceinline__ float frcp(float x) {
    return __builtin_amdgcn_rcpf(x);
}
// raw v_exp_f32 via COMPILER BUILTIN (hazards handled; no OCML fixup).
__device__ __forceinline__ float exp2b(float x) {
    return __builtin_amdgcn_exp2f(x);
}
__device__ __forceinline__ unsigned packbf2(float x0, float x1) {
    __hip_bfloat162 b = __float22bfloat162_rn(float2{x0, x1});
    union { __hip_bfloat162 b; unsigned u; } c; c.b = b; return c.u;
}
// tanh for the uniform Riccati prologue only
__device__ __forceinline__ float tanhfe(float x) {
    float e = __expf(2.0f * x);
    return fmaf(-2.0f, frcp(e + 1.0f), 1.0f);
}

// P = F P F^T for the constant-accel F (dt=0.2), in place (uniform Riccati only)
__device__ __forceinline__ void fpft(float (&P)[6][6]) {
    const float dt = 0.2f, hd = 0.02f;
    #pragma unroll
    for (int j = 0; j < 6; ++j) {
        float a0 = P[0][j] + dt * P[1][j] + hd * P[2][j];
        float a1 = P[1][j] + dt * P[2][j];
        float a3 = P[3][j] + dt * P[4][j] + hd * P[5][j];
        float a4 = P[4][j] + dt * P[5][j];
        P[0][j] = a0; P[1][j] = a1; P[3][j] = a3; P[4][j] = a4;
    }
    #pragma unroll
    for (int i = 0; i < 6; ++i) {
        float a0 = P[i][0] + dt * P[i][1] + hd * P[i][2];
        float a1 = P[i][1] + dt * P[i][2];
        float a3 = P[i][3] + dt * P[i][4] + hd * P[i][5];
        float a4 = P[i][4] + dt * P[i][5];
        P[i][0] = a0; P[i][1] = a1; P[i][3] = a3; P[i][4] = a4;
    }
}

// ------------------------------- main kernel ---------------------------------
// R13 = R12 + combine surgery (the last big scalar block):
//  - f32x2-PACKED combine: r processed in pairs; all add/mul/fma are v_pk_*
//    (bit-identical per element). ~120 scalar VALU -> ~64 pk ops/step.
//  - common-denominator cn: cn = [c*b + (eg-1)*a]*rcp(a*b), a=1+ef,
//    b=(1+ei)(eg+1) -> 1 rcp instead of 2 (-8 trans/step). Overflow audit:
//    |gates|<=11.5 -> a*b <= 2^67; den >= 1 (no underflow).
//  - packed feat-tanh (natural pairs from the packbf2 pairing).
// Carries R12: exp2b builtin everywhere, full exp2 constant-folding,
// zero-permlane layout, packed X/P, MFMA feat/gates/cmd.
__global__ __launch_bounds__(BLK, 2)
void kalman_lstm(const float* __restrict__ hist,
                 const float* __restrict__ psx, const float* __restrict__ psy,
                 const float* __restrict__ vsx, const float* __restrict__ vsy,
                 const float* __restrict__ asx, const float* __restrict__ asy,
                 const float* __restrict__ jerk, const float* __restrict__ coefG,
                 const float* __restrict__ GRv,
                 const float* __restrict__ cfW, const float* __restrict__ cfb,
                 const float* __restrict__ Wih, const float* __restrict__ Whh,
                 const float* __restrict__ bih, const float* __restrict__ bhh,
                 const float* __restrict__ coW, const float* __restrict__ cob,
                 float* __restrict__ out, int B, int len_pred)
{
    __shared__ float kf[216];  // [t*12..+11]=K pairs (paired layout); [180..215]=P_hist

    const int lane = threadIdx.x;
    const int e = lane & 15;              // element slot (MFMA n-index / D col)
    const int s = lane >> 4;              // quad (k-slice / D row group)
    const int b = blockIdx.x * EPB + e;

    const float dt = 0.2f, hd = 0.02f;
    const float g0 = dt * dt * dt / 6.0f, g1 = 0.02f, g2 = dt;
    const float NL2E  = -1.4426950408889634f;   // -log2(e)
    const float T2L2E =  2.8853900817779268f;   // 2*log2(e)
    float ga0 = g0 * tanhf(coefG[0]);
    float ga1 = g1 * tanhf(coefG[1]);
    float ga2 = g2 * tanhf(coefG[2]);
    float gb3 = g0 * tanhf(coefG[3]);
    float gb4 = g1 * tanhf(coefG[4]);
    float gb5 = g2 * tanhf(coefG[5]);

    // ---- batch-uniform Kalman-gain recursion (verbatim math; lane0 writes) ----
    // K stored PAIRED for packed consumption:
    //  t*12: {K0[0],K0[3], K0[1],K0[4], K0[2],K0[5], K1[0],K1[3], K1[1],K1[4], K1[2],K1[5]}
    {
        float j0 = jerk[0], j1 = jerk[1];
        float gr0 = GRv[0], gr1 = GRv[1];
        float R00 = gr0 * gr0, R01 = gr0 * gr1, R11 = gr1 * gr1;
        float qa[3] = {ga0 * j0, ga1 * j0, ga2 * j0};
        float qb[3] = {gb3 * j1, gb4 * j1, gb5 * j1};

        float Pk[6][6];
        #pragma unroll
        for (int i = 0; i < 6; ++i)
            #pragma unroll
            for (int j = 0; j < 6; ++j) Pk[i][j] = 0.0f;
        { float v;
          v = psx[0]; Pk[0][0] = v * v;
          v = vsx[0]; Pk[1][1] = v * v;
          v = asx[0]; Pk[2][2] = v * v;
          v = psy[0]; Pk[3][3] = v * v;
          v = vsy[0]; Pk[4][4] = v * v;
          v = asy[0]; Pk[5][5] = v * v; }

        #pragma unroll 1
        for (int t = 0; t < THIST; ++t) {
            fpft(Pk);
            #pragma unroll
            for (int i = 0; i < 3; ++i)
                #pragma unroll
                for (int j = 0; j < 3; ++j) {
                    Pk[i][j]         += qa[i] * qa[j];
                    Pk[3 + i][3 + j] += qb[i] * qb[j];
                }
            float S00 = Pk[0][0] + R00;
            float S01 = Pk[0][3] + R01;
            float S11 = Pk[3][3] + R11;
            float idet = 1.0f / (S00 * S11 - S01 * S01);
            float i00 =  S11 * idet, i01 = -S01 * idet, i11 = S00 * idet;
            float K0[6], K1[6];
            #pragma unroll
            for (int i = 0; i < 6; ++i) {
                K0[i] = Pk[i][0] * i00 + Pk[i][3] * i01;
                K1[i] = Pk[i][0] * i01 + Pk[i][3] * i11;
            }
            if (lane == 0) {
                #pragma unroll
                for (int i = 0; i < 3; ++i) {
                    kf[t * 12 + 2 * i]     = K0[i];
                    kf[t * 12 + 2 * i + 1] = K0[3 + i];
                    kf[t * 12 + 6 + 2 * i]     = K1[i];
                    kf[t * 12 + 6 + 2 * i + 1] = K1[3 + i];
                }
            }
            #pragma unroll
            for (int i = 0; i < 6; ++i) {
                Pk[i][1] -= K0[1] * Pk[i][0] + K1[1] * Pk[i][3];
                Pk[i][2] -= K0[2] * Pk[i][0] + K1[2] * Pk[i][3];
                Pk[i][4] -= K0[4] * Pk[i][0] + K1[4] * Pk[i][3];
                Pk[i][5] -= K0[5] * Pk[i][0] + K1[5] * Pk[i][3];
                float t0 = Pk[i][0] - (K0[0] * Pk[i][0] + K1[0] * Pk[i][3]);
                float t3 = Pk[i][3] - (K0[3] * Pk[i][0] + K1[3] * Pk[i][3]);
                Pk[i][0] = t0; Pk[i][3] = t3;
            }
        }
        if (lane == 0) {
            #pragma unroll
            for (int i = 0; i < 6; ++i)
                #pragma unroll
                for (int j = 0; j < 6; ++j) kf[180 + i * 6 + j] = Pk[i][j];
        }
    }

    // ---- LSTM weights, ROW-PERMUTED + exp2-folded scales ----
    // Tile nt: gate G=nt>>1 (0=i,1=f,2=g,3=o), blk=nt&1.
    // Lane-e A-row = W row G*32 + 8*(e>>2) + 4*blk + (e&3)  (bijective per G).
    // D row m=4s+r holds gate value for feature 8s+4*blk+r == lane's k-slice.
    // Scales: sigmoid gates x(-log2e); g-gate x(2log2e).
    s16x8 wih_h[8], whh_h[8];
    #pragma unroll
    for (int nt = 0; nt < 8; ++nt) {
        int G = nt >> 1, blk = nt & 1;
        float sc = (G == 2) ? T2L2E : NL2E;
        int base = (G * 32 + 8 * (e >> 2) + 4 * blk + (e & 3)) * NF + s * 8;
        frag_u ih_h, hh_h;
        #pragma unroll
        for (int q = 0; q < 4; ++q) {
            ih_h.u[q] = packbf2(sc * Wih[base + 2 * q], sc * Wih[base + 2 * q + 1]);
            hh_h.u[q] = packbf2(sc * Whh[base + 2 * q], sc * Whh[base + 2 * q + 1]);
        }
        wih_h[nt] = ih_h.v;
        whh_h[nt] = hh_h.v;
    }

    // bias fragments (register C-in), same row permutation + scales
    f32x4 biasF[8];
    #pragma unroll
    for (int nt = 0; nt < 8; ++nt) {
        int G = nt >> 1, blk = nt & 1;
        float sc = (G == 2) ? T2L2E : NL2E;
        int base = G * 32 + 8 * s + 4 * blk;
        f32x4 bi = *(const f32x4*)&bih[base];
        f32x4 bh = *(const f32x4*)&bhh[base];
        biasF[nt] = (bi + bh) * sc;
    }

    // feat-MFMA A-frags, row-permuted AND x(2log2e): tile0 lane-e row ->
    // feature 8*(e>>2)+(e&3), tile1 -> +4. s=0 lanes carry cfW + cfb at k=6.
    s16x8 cfwA0, cfwA1;
    {
        frag_u fa0, fa1; fa0.v = (s16x8)0; fa1.v = (s16x8)0;
        if (s == 0) {
            int f0 = 8 * (e >> 2) + (e & 3);
            int f1 = f0 + 4;
            const float* w0 = cfW + f0 * 6;
            const float* w1 = cfW + f1 * 6;
            fa0.u[0] = packbf2(T2L2E * w0[0], T2L2E * w0[1]);
            fa0.u[1] = packbf2(T2L2E * w0[2], T2L2E * w0[3]);
            fa0.u[2] = packbf2(T2L2E * w0[4], T2L2E * w0[5]);
            fa0.u[3] = packbf2(T2L2E * cfb[f0], 0.0f);
            fa1.u[0] = packbf2(T2L2E * w1[0], T2L2E * w1[1]);
            fa1.u[1] = packbf2(T2L2E * w1[2], T2L2E * w1[3]);
            fa1.u[2] = packbf2(T2L2E * w1[4], T2L2E * w1[5]);
            fa1.u[3] = packbf2(T2L2E * cfb[f1], 0.0f);
        }
        cfwA0 = fa0.v; cfwA1 = fa1.v;
    }
    // cmd-MFMA A-frag: coW rows replicated 4x -> D[m=4s+r] = cmd_r in every lane
    s16x8 cmdA;
    {
        frag_u ca;
        const float* cp = coW + (e & 3) * NF + 8 * s;
        #pragma unroll
        for (int q = 0; q < 4; ++q)
            ca.u[q] = packbf2(cp[2 * q], cp[2 * q + 1]);
        cmdA = ca.v;
    }
    f32x4 cobC = {cob[0], cob[1], cob[2], cob[3]};

    // ---- Kalman state X, PACKED: Xa={X0,X3}, Xb={X1,X4}, Xc={X2,X5} ----
    const float2* hist2 = (const float2*)hist;
    float2 z0 = hist2[b];
    float2 z1 = hist2[B + b];
    f32x2 Xa = {z0.x, (z1.y - z0.y) / dt};
    f32x2 Xb = {(z1.x - z0.x) / dt, 0.0f};
    f32x2 Xc = {0.0f, 0.0f};

    f32x2 creg2[4];   // [2*blk+rp] = {cn(r=2rp), cn(r=2rp+1)}
    #pragma unroll
    for (int j = 0; j < 4; ++j) creg2[j] = (f32x2){0.0f, 0.0f};
    s16x8 ah_h = (s16x8)0;

    __syncthreads();   // one-time: kf visible

    auto lstm_step = [&]() {
        // ---- feat via MFMA: featpre' = 2log2e*(cfW@X + cfb) ----
        frag_u xb;
        xb.u[0] = packbf2(Xa.x, Xb.x);            // X0,X1
        xb.u[1] = packbf2(Xc.x, Xa.y);            // X2,X3
        xb.u[2] = packbf2(Xb.y, Xc.y);            // X4,X5
        xb.u[3] = 0x00003f80u;                    // k6 = bf16(1.0)
        const f32x4 zc4 = {0.0f, 0.0f, 0.0f, 0.0f};
        f32x4 fp0 = __builtin_amdgcn_mfma_f32_16x16x32_bf16(cfwA0, xb.v, zc4, 0, 0, 0);
        f32x4 fp1 = __builtin_amdgcn_mfma_f32_16x16x32_bf16(cfwA1, xb.v, zc4, 0, 0, 0);
        // packed tanh pair: t = 1 - 2*rcp(2^xp + 1); pairs match packbf2 pairs
        auto tanh2p = [](float x0, float x1) -> f32x2 {
            f32x2 eg2 = {exp2b(x0), exp2b(x1)};
            f32x2 gp  = eg2 + 1.0f;
            f32x2 rd  = {frcp(gp.x), frcp(gp.y)};
            return (f32x2){1.0f, 1.0f} - 2.0f * rd;
        };
        frag_u af;
        { f32x2 t = tanh2p(fp0[0], fp0[1]); af.u[0] = packbf2(t.x, t.y); }
        { f32x2 t = tanh2p(fp0[2], fp0[3]); af.u[1] = packbf2(t.x, t.y); }
        { f32x2 t = tanh2p(fp1[0], fp1[1]); af.u[2] = packbf2(t.x, t.y); }
        { f32x2 t = tanh2p(fp1[2], fp1[3]); af.u[3] = packbf2(t.x, t.y); }

        // ---- gates = Wih@feat + Whh@h + bias (register C-in) ----
        f32x4 acc[8];
        #pragma unroll
        for (int nt = 0; nt < 8; ++nt) {
            acc[nt] = __builtin_amdgcn_mfma_f32_16x16x32_bf16(wih_h[nt], af.v, biasF[nt], 0, 0, 0);
            acc[nt] = __builtin_amdgcn_mfma_f32_16x16x32_bf16(whh_h[nt], ah_h, acc[nt], 0, 0, 0);
        }

        // ---- PACKED combine (r-pairs); common-denominator cn:
        //   a=1+ef, b=(1+ei)(eg+1); cn = [c*b + (eg-1)*a] * rcp(a*b)
        //   hv = (ec-1) * rcp((1+eo)(ec+1)), ec = 2^(2log2e*cn)
        unsigned whx[2][2];
        #pragma unroll
        for (int blk = 0; blk < 2; ++blk) {
            #pragma unroll
            for (int rp = 0; rp < 2; ++rp) {
                int r0 = 2 * rp, r1 = 2 * rp + 1;
                f32x2 ei2 = {exp2b(acc[0 + blk][r0]), exp2b(acc[0 + blk][r1])};
                f32x2 ef2 = {exp2b(acc[2 + blk][r0]), exp2b(acc[2 + blk][r1])};
                f32x2 eg2 = {exp2b(acc[4 + blk][r0]), exp2b(acc[4 + blk][r1])};
                f32x2 eo2 = {exp2b(acc[6 + blk][r0]), exp2b(acc[6 + blk][r1])};
                f32x2 a2  = ef2 + 1.0f;
                f32x2 b2  = (ei2 + 1.0f) * (eg2 + 1.0f);
                f32x2 num = (eg2 - 1.0f) * a2 + creg2[2 * blk + rp] * b2;
                f32x2 den = a2 * b2;
                f32x2 rd  = {frcp(den.x), frcp(den.y)};
                f32x2 cn2 = num * rd;
                creg2[2 * blk + rp] = cn2;
                f32x2 cns = T2L2E * cn2;
                f32x2 ec2 = {exp2b(cns.x), exp2b(cns.y)};
                f32x2 d2  = (eo2 + 1.0f) * (ec2 + 1.0f);
                f32x2 rd2 = {frcp(d2.x), frcp(d2.y)};
                f32x2 hv2 = (ec2 - 1.0f) * rd2;
                whx[blk][rp] = packbf2(hv2.x, hv2.y);
            }
        }

        // hv pair (blk,rp) = h[8s+4blk+2rp..+1] -> ah fragment packs DIRECTLY
        frag_u ahh;
        ahh.u[0] = whx[0][0];
        ahh.u[1] = whx[0][1];
        ahh.u[2] = whx[1][0];
        ahh.u[3] = whx[1][1];
        ah_h = ahh.v;
    };

    // ------------- history phase: packed X update, uniform K from LDS -------------
    float2 zc = z1;
    #pragma unroll 1
    for (int t = 0; t < THIST; ++t) {
        int tn = (t + 2 < 16) ? (t + 2) : 15;
        float2 zn = hist2[(size_t)tn * B + b];
        f32x4 k0 = *(const f32x4*)&kf[t * 12];       // {K00,K03,K01,K04}
        f32x4 k1 = *(const f32x4*)&kf[t * 12 + 4];   // {K02,K05,K10,K13}
        f32x4 k2 = *(const f32x4*)&kf[t * 12 + 8];   // {K11,K14,K12,K15}

        lstm_step();

        Xa = Xa + dt * Xb + hd * Xc;
        Xb = Xb + dt * Xc;
        float y0 = zc.x - Xa.x, y1 = zc.y - Xa.y;
        f32x2 kA0 = {k0[0], k0[1]}, kB0 = {k0[2], k0[3]}, kC0 = {k1[0], k1[1]};
        f32x2 kA1 = {k1[2], k1[3]}, kB1 = {k2[0], k2[1]}, kC1 = {k2[2], k2[3]};
        Xa = Xa + kA0 * y0 + kA1 * y1;
        Xb = Xb + kB0 * y0 + kB1 * y1;
        Xc = Xc + kC0 * y0 + kC1 * y1;
        zc = zn;
    }

    // P init; x/y blocks PACKED {x, y}
    f32x2 pxy00 = {kf[180], kf[201]}, pxy01 = {kf[181], kf[202]},
          pxy02 = {kf[182], kf[203]}, pxy11 = {kf[187], kf[208]},
          pxy12 = {kf[188], kf[209]}, pxy22 = {kf[194], kf[214]};
    float c00 = kf[183], c01 = kf[184], c02 = kf[185],
          c10 = kf[189], c11 = kf[190], c12 = kf[191],
          c20 = kf[195], c21 = kf[196], c22 = kf[197];
    const f32x2 gaP0 = {ga0, gb3}, gaP1 = {ga1, gb4}, gaP2 = {ga2, gb5};

    // ---------------- prediction phase ----------------
    #pragma unroll 1
    for (int tp = 0; tp < len_pred; ++tp) {
        lstm_step();

        // cmd = coW@h + cob via one MFMA; every lane gets cmd0..3 in D regs
        f32x4 cm = __builtin_amdgcn_mfma_f32_16x16x32_bf16(cmdA, ah_h, cobC, 0, 0, 0);
        f32x2 cmdP  = {cm[0], cm[1]};
        f32x2 cmd23 = {cm[2], cm[3]};

        Xa = Xa + dt * Xb + hd * Xc + g0 * cmdP;
        Xb = Xb + dt * Xc + g1 * cmdP;
        Xc = Xc + g2 * cmdP;

        // P = F P F^T + Gs Gs^T; x/y blocks packed, cross scalar
        f32x2 gsA = gaP0 * cmd23;   // {gs0, gs3}
        f32x2 gsB = gaP1 * cmd23;   // {gs1, gs4}
        f32x2 gsC = gaP2 * cmd23;   // {gs2, gs5}
        {
            f32x2 r00 = pxy00 + dt * pxy01 + hd * pxy02;
            f32x2 r01 = pxy01 + dt * pxy11 + hd * pxy12;
            f32x2 r02 = pxy02 + dt * pxy12 + hd * pxy22;
            f32x2 r11 = pxy11 + dt * pxy12;
            f32x2 r12 = pxy12 + dt * pxy22;
            pxy00 = r00 + dt * r01 + hd * r02;
            pxy01 = r01 + dt * r02;
            pxy02 = r02;
            pxy11 = r11 + dt * r12;
            pxy12 = r12;
            pxy00 += gsA * gsA; pxy01 += gsA * gsB; pxy02 += gsA * gsC;
            pxy11 += gsB * gsB; pxy12 += gsB * gsC; pxy22 += gsC * gsC;
        }
        {   // cross block c = A c A^T + gs_x gs_y^T (scalar)
            float gs0 = gsA.x, gs1 = gsB.x, gs2 = gsC.x;
            float gs3 = gsA.y, gs4 = gsB.y, gs5 = gsC.y;
            float q00 = c00 + dt * c10 + hd * c20;
            float q01 = c01 + dt * c11 + hd * c21;
            float q02 = c02 + dt * c12 + hd * c22;
            float q10 = c10 + dt * c20;
            float q11 = c11 + dt * c21;
            float q12 = c12 + dt * c22;
            c00 = q00 + dt * q01 + hd * q02;
            c01 = q01 + dt * q02;
            c02 = q02;
            c10 = q10 + dt * q11 + hd * q12;
            c11 = q11 + dt * q12;
            c12 = q12;
            float n20 = c20 + dt * c21 + hd * c22;
            float n21 = c21 + dt * c22;
            c20 = n20; c21 = n21;
            c00 += gs0 * gs3; c01 += gs0 * gs4; c02 += gs0 * gs5;
            c10 += gs1 * gs3; c11 += gs1 * gs4; c12 += gs1 * gs5;
            c20 += gs2 * gs3; c21 += gs2 * gs4; c22 += gs2 * gs5;
        }

        float sx = sqrtf(pxy00.x), sy = sqrtf(pxy00.y);
        float rho = c00 / (sx * sy);
        if (s == 0) {
            size_t o = ((size_t)tp * B + b) * 5u;
            out[o + 0] = Xa.x;
            out[o + 1] = Xa.y;
            out[o + 2] = sx;
            out[o + 3] = sy;
            out[o + 4] = rho;
        }
    }
}

extern "C" void kernel_launch(void* const* d_in, const int* in_sizes, int n_in,
                              void* d_out, int out_size, void* d_ws, size_t ws_size,
                              hipStream_t stream) {
    const int T = 16;
    const int B = in_sizes[0] / (2 * T);      // 32768
    const int len_pred = out_size / (5 * B);  // 25
    (void)d_ws; (void)ws_size; (void)n_in;

    const int grid = (B + EPB - 1) / EPB;     // one wave per 16 elements
    kalman_lstm<<<grid, BLK, 0, stream>>>(
        (const float*)d_in[0],  (const float*)d_in[1],  (const float*)d_in[2],
        (const float*)d_in[3],  (const float*)d_in[4],  (const float*)d_in[5],
        (const float*)d_in[6],  (const float*)d_in[7],  (const float*)d_in[8],
        (const float*)d_in[9],  (const float*)d_in[10], (const float*)d_in[11],
        (const float*)d_in[12], (const float*)d_in[13], (const float*)d_in[14],
        (const float*)d_in[15], (const float*)d_in[16], (const float*)d_in[17],
        (float*)d_out, B, len_pred);
}